// Round 13
// baseline (84.848 us; speedup 1.0000x reference)
//
#include <hip/hip_runtime.h>
#include <math.h>

#define B 16
#define F 8
#define C 256
#define HW 1024
#define NROWS (B*F*C)       // 32768
#define KC 205              // ceil(0.8*256)

typedef float f4 __attribute__((ext_vector_type(4)));

// ---------------------------------------------------------------------------
// K1: per-(b,f,c) row stats over the 1024-element h*w plane. (unchanged;
// measured ~13 us, ~10.6 TB/s L3-assisted)
// ---------------------------------------------------------------------------
__global__ __launch_bounds__(256) void k_rowstat(const float* __restrict__ x,
                                                 float* __restrict__ sums,
                                                 float* __restrict__ maxs) {
    const int wave = threadIdx.x >> 6;
    const int lane = threadIdx.x & 63;
    const int row0 = blockIdx.x * 8 + wave * 2;
    const float* p0 = x + (size_t)row0 * HW + lane * 4;
    const float* p1 = p0 + HW;

    float4 a0 = *reinterpret_cast<const float4*>(p0);
    float4 a1 = *reinterpret_cast<const float4*>(p0 + 256);
    float4 a2 = *reinterpret_cast<const float4*>(p0 + 512);
    float4 a3 = *reinterpret_cast<const float4*>(p0 + 768);
    float4 b0 = *reinterpret_cast<const float4*>(p1);
    float4 b1 = *reinterpret_cast<const float4*>(p1 + 256);
    float4 b2 = *reinterpret_cast<const float4*>(p1 + 512);
    float4 b3 = *reinterpret_cast<const float4*>(p1 + 768);

    float s0 = (((a0.x + a0.y) + (a0.z + a0.w)) + ((a1.x + a1.y) + (a1.z + a1.w)))
             + (((a2.x + a2.y) + (a2.z + a2.w)) + ((a3.x + a3.y) + (a3.z + a3.w)));
    float m0 = fmaxf(fmaxf(fmaxf(fmaxf(a0.x, a0.y), fmaxf(a0.z, a0.w)),
                           fmaxf(fmaxf(a1.x, a1.y), fmaxf(a1.z, a1.w))),
                     fmaxf(fmaxf(fmaxf(a2.x, a2.y), fmaxf(a2.z, a2.w)),
                           fmaxf(fmaxf(a3.x, a3.y), fmaxf(a3.z, a3.w))));
    float s1 = (((b0.x + b0.y) + (b0.z + b0.w)) + ((b1.x + b1.y) + (b1.z + b1.w)))
             + (((b2.x + b2.y) + (b2.z + b2.w)) + ((b3.x + b3.y) + (b3.z + b3.w)));
    float m1 = fmaxf(fmaxf(fmaxf(fmaxf(b0.x, b0.y), fmaxf(b0.z, b0.w)),
                           fmaxf(fmaxf(b1.x, b1.y), fmaxf(b1.z, b1.w))),
                     fmaxf(fmaxf(fmaxf(b2.x, b2.y), fmaxf(b2.z, b2.w)),
                           fmaxf(fmaxf(b3.x, b3.y), fmaxf(b3.z, b3.w))));

#pragma unroll
    for (int off = 32; off > 0; off >>= 1) {
        s0 += __shfl_down(s0, off);
        m0 = fmaxf(m0, __shfl_down(m0, off));
        s1 += __shfl_down(s1, off);
        m1 = fmaxf(m1, __shfl_down(m1, off));
    }
    if (lane == 0) {
        sums[row0] = s0; maxs[row0] = m0;
        sums[row0 + 1] = s1; maxs[row0 + 1] = m1;
    }
}

// ---------------------------------------------------------------------------
// K2: full attention, merged. 16 blocks x 1024 threads (16 waves).
// All weight reads wave-coalesced (64 lanes x float4 over ONE row = 16 shared
// cache lines/instr; 512 KB of weight lines per CU streams at L2 rate).
//   tpool (wave f) -> 8x8 time MLP -> ta    (WTA time: k=8 -> sal_t = ta)
//   chan pool q-split -> vavg/vmax
//   layer1: wave w rows h=16w..16w+15, float4 dot + shfl reduce -> hsum
//   layer2: same pattern with w2 -> ca
//   WTA rank-count q-split; srow[b,f,c] = ta[f]*ca*mask (mask^2==mask)
// ---------------------------------------------------------------------------
__global__ __launch_bounds__(1024) void k_att(const float* __restrict__ sums,
                                              const float* __restrict__ maxs,
                                              const float* __restrict__ tw1,
                                              const float* __restrict__ tw2,
                                              const float* __restrict__ w1,
                                              const float* __restrict__ w2,
                                              float* __restrict__ srow) {
    __shared__ float tavg[F], tmx[F], th[F], ta_s[F];
    __shared__ __align__(16) float vavg[C], vmax[C], hsum[C], ca[C];
    __shared__ float pa[4][C], pm[4][C];
    __shared__ float sal[C];
    const int b    = blockIdx.x;
    const int t    = threadIdx.x;        // 0..1023
    const int wave = t >> 6;             // 0..15
    const int lane = t & 63;
    const int c    = t & 255;
    const int q    = t >> 8;             // 0..3

    // tpool: wave f (0..7) reduces feature f over 256 channels
    if (wave < F) {
        const float* sp = sums + (b * F + wave) * C;
        const float* mp = maxs + (b * F + wave) * C;
        float s = (sp[lane] + sp[lane + 64]) + (sp[lane + 128] + sp[lane + 192]);
        float m = fmaxf(fmaxf(mp[lane], mp[lane + 64]),
                        fmaxf(mp[lane + 128], mp[lane + 192]));
#pragma unroll
        for (int off = 32; off > 0; off >>= 1) {
            s += __shfl_down(s, off);
            m = fmaxf(m, __shfl_down(m, off));
        }
        if (lane == 0) { tavg[wave] = s * (1.f / (float)(C * HW)); tmx[wave] = m; }
    }
    __syncthreads();

    // time MLP (8x8), threads 0..7
    if (t < F) {
        float ha = 0.f, hm = 0.f;
        for (int n = 0; n < F; ++n) {
            float w = tw1[t * F + n];
            ha += w * tavg[n];
            hm += w * tmx[n];
        }
        th[t] = fmaxf(ha, 0.f) + fmaxf(hm, 0.f);
    }
    __syncthreads();
    if (t < F) {
        float o = 0.f;
        for (int h = 0; h < F; ++h) o += tw2[t * F + h] * th[h];
        ta_s[t] = 1.f / (1.f + expf(-o));
    }
    __syncthreads();

    // chan pool, q-split over f pairs {2q, 2q+1}
    {
        const int f0 = 2 * q, f1 = 2 * q + 1;
        const float wa = ta_s[f0], wb = ta_s[f1];
        pa[q][c] = wa * sums[(b * F + f0) * C + c] + wb * sums[(b * F + f1) * C + c];
        pm[q][c] = fmaxf(wa * maxs[(b * F + f0) * C + c],
                         wb * maxs[(b * F + f1) * C + c]);
    }
    __syncthreads();
    if (q == 0) {
        vavg[c] = ((pa[0][c] + pa[1][c]) + (pa[2][c] + pa[3][c])) * (1.f / (float)(F * HW));
        vmax[c] = fmaxf(fmaxf(pm[0][c], pm[1][c]), fmaxf(pm[2][c], pm[3][c]));
    }
    __syncthreads();

    // layer1: wave w handles hidden rows h = 16w .. 16w+15, coalesced
    {
        const float4 va = reinterpret_cast<const float4*>(vavg)[lane];
        const float4 vm = reinterpret_cast<const float4*>(vmax)[lane];
#pragma unroll 4
        for (int k = 0; k < 16; ++k) {
            const int h = wave * 16 + k;
            float4 w = reinterpret_cast<const float4*>(w1 + h * C)[lane];
            float ha = (w.x * va.x + w.y * va.y) + (w.z * va.z + w.w * va.w);
            float hm = (w.x * vm.x + w.y * vm.y) + (w.z * vm.z + w.w * vm.w);
#pragma unroll
            for (int off = 32; off > 0; off >>= 1) {
                ha += __shfl_down(ha, off);
                hm += __shfl_down(hm, off);
            }
            if (lane == 0) hsum[h] = fmaxf(ha, 0.f) + fmaxf(hm, 0.f);
        }
    }
    __syncthreads();

    // layer2 + sigmoid: wave w handles out channels cc = 16w .. 16w+15
    {
        const float4 hv = reinterpret_cast<const float4*>(hsum)[lane];
#pragma unroll 4
        for (int k = 0; k < 16; ++k) {
            const int cc = wave * 16 + k;
            float4 w = reinterpret_cast<const float4*>(w2 + cc * C)[lane];
            float o = (w.x * hv.x + w.y * hv.y) + (w.z * hv.z + w.w * hv.w);
#pragma unroll
            for (int off = 32; off > 0; off >>= 1) o += __shfl_down(o, off);
            if (lane == 0) ca[cc] = 1.f / (1.f + expf(-o));
        }
    }
    __syncthreads();

    // WTA rank count, q-split over j; keep iff #{j: ca_j > ca_c} < KC
    {
        const float cav = ca[c];
        int cnt = 0;
        const int j0 = q * 64;
        for (int j = 0; j < 64; ++j) cnt += (ca[j0 + j] > cav);
        pm[q][c] = (float)cnt;
    }
    __syncthreads();
    if (q == 0) {
        int rank = (int)((pm[0][c] + pm[1][c]) + (pm[2][c] + pm[3][c]));
        sal[c] = (rank < KC) ? ca[c] : 0.f;
    }
    __syncthreads();

    // srow[b,f,c] = ta[f] * sal[c]; thread (c,q) writes f = q and q+4
    {
        const float scv = sal[c];
        srow[b * (F * C) + q * C + c]       = ta_s[q] * scv;
        srow[b * (F * C) + (q + 4) * C + c] = ta_s[q + 4] * scv;
    }
}

// ---------------------------------------------------------------------------
// K3: out = x * srow[row]. 2048 blocks x 256 threads; block owns 16 rows.
// Measured ~41 us incl. gap (R9 within-probe) = mixed-stream copy floor.
// Zero rows (~20%) skip the x read. Plain stores.
// ---------------------------------------------------------------------------
__global__ __launch_bounds__(256) void k_scale(const float* __restrict__ x,
                                               const float* __restrict__ srow,
                                               float* __restrict__ out) {
    const int t    = threadIdx.x;
    const int row0 = blockIdx.x * 16;
    const f4* x4 = reinterpret_cast<const f4*>(x);
    f4* o4 = reinterpret_cast<f4*>(out);

    float sc[16];
#pragma unroll
    for (int i = 0; i < 16; ++i) sc[i] = srow[row0 + i];

#pragma unroll
    for (int g = 0; g < 4; ++g) {
        const size_t base = (size_t)(row0 + g * 4) * 256 + t;
        const float s0 = sc[g*4], s1 = sc[g*4+1], s2 = sc[g*4+2], s3 = sc[g*4+3];
        const f4 z = {0.f, 0.f, 0.f, 0.f};
        f4 v0 = z, v1 = z, v2 = z, v3 = z;
        if (s0 != 0.f) v0 = x4[base];
        if (s1 != 0.f) v1 = x4[base + 256];
        if (s2 != 0.f) v2 = x4[base + 512];
        if (s3 != 0.f) v3 = x4[base + 768];
        v0 *= s0; v1 *= s1; v2 *= s2; v3 *= s3;
        o4[base]       = v0;
        o4[base + 256] = v1;
        o4[base + 512] = v2;
        o4[base + 768] = v3;
    }
}

extern "C" void kernel_launch(void* const* d_in, const int* in_sizes, int n_in,
                              void* d_out, int out_size, void* d_ws, size_t ws_size,
                              hipStream_t stream) {
    const float* x     = (const float*)d_in[0];
    const float* ta_w1 = (const float*)d_in[1];
    const float* ta_w2 = (const float*)d_in[2];
    const float* ca_w1 = (const float*)d_in[3];
    const float* ca_w2 = (const float*)d_in[4];
    float* out = (float*)d_out;

    float* ws   = (float*)d_ws;
    float* sums = ws;                    // [32768]
    float* maxs = ws + NROWS;            // [32768]
    float* srow = ws + 2 * NROWS;        // [32768]

    k_rowstat<<<NROWS / 8, 256, 0, stream>>>(x, sums, maxs);
    k_att<<<B, 1024, 0, stream>>>(sums, maxs, ta_w1, ta_w2, ca_w1, ca_w2, srow);
    k_scale<<<2048, 256, 0, stream>>>(x, srow, out);
}

// Round 14
// 71.633 us; speedup vs baseline: 1.1845x; 1.1845x over previous
//
#include <hip/hip_runtime.h>
#include <math.h>

#define B 16
#define F 8
#define C 256
#define HW 1024
#define NROWS (B*F*C)       // 32768
#define KC 205              // ceil(0.8*256)

typedef float f4 __attribute__((ext_vector_type(4)));

// ---------------------------------------------------------------------------
// R14 = exact revert to R12 (71.66 us, passed). R13's 16-block merge regressed
// +13 us: with 16 blocks each CU pulls ALL 512 KB of w1+w2 through its own
// miss path; the 256-block split divides per-CU line demand by 16 and wins
// despite one extra dispatch gap. Per-CU cache-line demand governs.
// ---------------------------------------------------------------------------

// ---------------------------------------------------------------------------
// K1: per-(b,f,c) row stats over the 1024-element h*w plane.
// 2 rows per wave; all 8 dwordx4 loads in flight before reducing.
// 4096 blocks x 256 threads. Measured ~13 us (~10.3 TB/s, L3-assisted).
// ---------------------------------------------------------------------------
__global__ __launch_bounds__(256) void k_rowstat(const float* __restrict__ x,
                                                 float* __restrict__ sums,
                                                 float* __restrict__ maxs) {
    const int wave = threadIdx.x >> 6;
    const int lane = threadIdx.x & 63;
    const int row0 = blockIdx.x * 8 + wave * 2;
    const float* p0 = x + (size_t)row0 * HW + lane * 4;
    const float* p1 = p0 + HW;

    float4 a0 = *reinterpret_cast<const float4*>(p0);
    float4 a1 = *reinterpret_cast<const float4*>(p0 + 256);
    float4 a2 = *reinterpret_cast<const float4*>(p0 + 512);
    float4 a3 = *reinterpret_cast<const float4*>(p0 + 768);
    float4 b0 = *reinterpret_cast<const float4*>(p1);
    float4 b1 = *reinterpret_cast<const float4*>(p1 + 256);
    float4 b2 = *reinterpret_cast<const float4*>(p1 + 512);
    float4 b3 = *reinterpret_cast<const float4*>(p1 + 768);

    float s0 = (((a0.x + a0.y) + (a0.z + a0.w)) + ((a1.x + a1.y) + (a1.z + a1.w)))
             + (((a2.x + a2.y) + (a2.z + a2.w)) + ((a3.x + a3.y) + (a3.z + a3.w)));
    float m0 = fmaxf(fmaxf(fmaxf(fmaxf(a0.x, a0.y), fmaxf(a0.z, a0.w)),
                           fmaxf(fmaxf(a1.x, a1.y), fmaxf(a1.z, a1.w))),
                     fmaxf(fmaxf(fmaxf(a2.x, a2.y), fmaxf(a2.z, a2.w)),
                           fmaxf(fmaxf(a3.x, a3.y), fmaxf(a3.z, a3.w))));
    float s1 = (((b0.x + b0.y) + (b0.z + b0.w)) + ((b1.x + b1.y) + (b1.z + b1.w)))
             + (((b2.x + b2.y) + (b2.z + b2.w)) + ((b3.x + b3.y) + (b3.z + b3.w)));
    float m1 = fmaxf(fmaxf(fmaxf(fmaxf(b0.x, b0.y), fmaxf(b0.z, b0.w)),
                           fmaxf(fmaxf(b1.x, b1.y), fmaxf(b1.z, b1.w))),
                     fmaxf(fmaxf(fmaxf(b2.x, b2.y), fmaxf(b2.z, b2.w)),
                           fmaxf(fmaxf(b3.x, b3.y), fmaxf(b3.z, b3.w))));

#pragma unroll
    for (int off = 32; off > 0; off >>= 1) {
        s0 += __shfl_down(s0, off);
        m0 = fmaxf(m0, __shfl_down(m0, off));
        s1 += __shfl_down(s1, off);
        m1 = fmaxf(m1, __shfl_down(m1, off));
    }
    if (lane == 0) {
        sums[row0] = s0; maxs[row0] = m0;
        sums[row0 + 1] = s1; maxs[row0 + 1] = m1;
    }
}

// ---------------------------------------------------------------------------
// K2a: layer-1 of channel MLP, spread over 256 blocks = (b, g).
// Redundant per block (cheap): tpool + 8x8 time MLP -> ta  (WTA time: k=8 ->
// mask_t==1 -> sal_t = ta). Then COALESCED layer1 for 16 hidden units:
// wave-cooperative dot (lanes share one w1 row), shfl-reduce.
// 16 KB of weight lines per block.
// ---------------------------------------------------------------------------
__global__ __launch_bounds__(256) void k_l1(const float* __restrict__ sums,
                                            const float* __restrict__ maxs,
                                            const float* __restrict__ tw1,
                                            const float* __restrict__ tw2,
                                            const float* __restrict__ w1,
                                            float* __restrict__ ta_g,
                                            float* __restrict__ hsum_g) {
    __shared__ float tavg[F], tmx[F], th[F], ta_s[F];
    __shared__ __align__(16) float vavg[C], vmax[C];
    const int b = blockIdx.x >> 4, g = blockIdx.x & 15;
    const int t = threadIdx.x, wave = t >> 6, lane = t & 63;

    for (int f = wave; f < F; f += 4) {
        const float* sp = sums + (b * F + f) * C;
        const float* mp = maxs + (b * F + f) * C;
        float s = (sp[lane] + sp[lane + 64]) + (sp[lane + 128] + sp[lane + 192]);
        float m = fmaxf(fmaxf(mp[lane], mp[lane + 64]),
                        fmaxf(mp[lane + 128], mp[lane + 192]));
#pragma unroll
        for (int off = 32; off > 0; off >>= 1) {
            s += __shfl_down(s, off);
            m = fmaxf(m, __shfl_down(m, off));
        }
        if (lane == 0) { tavg[f] = s * (1.f / (float)(C * HW)); tmx[f] = m; }
    }
    __syncthreads();

    if (t < F) {
        float ha = 0.f, hm = 0.f;
        for (int n = 0; n < F; ++n) {
            float w = tw1[t * F + n];
            ha += w * tavg[n];
            hm += w * tmx[n];
        }
        th[t] = fmaxf(ha, 0.f) + fmaxf(hm, 0.f);
    }
    __syncthreads();
    if (t < F) {
        float o = 0.f;
        for (int h = 0; h < F; ++h) o += tw2[t * F + h] * th[h];
        ta_s[t] = 1.f / (1.f + expf(-o));
    }
    __syncthreads();
    if (g == 0 && t < F) ta_g[b * F + t] = ta_s[t];

    {
        float s = 0.f, m = -INFINITY;
        for (int f = 0; f < F; ++f) {
            float w = ta_s[f];
            s += w * sums[(b * F + f) * C + t];
            m = fmaxf(m, w * maxs[(b * F + f) * C + t]);
        }
        vavg[t] = s * (1.f / (float)(F * HW));
        vmax[t] = m;
    }
    __syncthreads();

    const float4 va = reinterpret_cast<const float4*>(vavg)[lane];
    const float4 vm = reinterpret_cast<const float4*>(vmax)[lane];
#pragma unroll
    for (int k = 0; k < 4; ++k) {
        const int h = 16 * g + wave * 4 + k;
        float4 w = reinterpret_cast<const float4*>(w1 + h * C)[lane];
        float ha = (w.x * va.x + w.y * va.y) + (w.z * va.z + w.w * va.w);
        float hm = (w.x * vm.x + w.y * vm.y) + (w.z * vm.z + w.w * vm.w);
#pragma unroll
        for (int off = 32; off > 0; off >>= 1) {
            ha += __shfl_down(ha, off);
            hm += __shfl_down(hm, off);
        }
        if (lane == 0) hsum_g[b * C + h] = fmaxf(ha, 0.f) + fmaxf(hm, 0.f);
    }
}

// ---------------------------------------------------------------------------
// K2b: layer-2 + sigmoid, 256 blocks = (b, g), coalesced w2 rows.
// ---------------------------------------------------------------------------
__global__ __launch_bounds__(256) void k_l2(const float* __restrict__ hsum_g,
                                            const float* __restrict__ w2,
                                            float* __restrict__ ca_g) {
    __shared__ __align__(16) float hs[C];
    const int b = blockIdx.x >> 4, g = blockIdx.x & 15;
    const int t = threadIdx.x, wave = t >> 6, lane = t & 63;

    hs[t] = hsum_g[b * C + t];
    __syncthreads();
    const float4 hv = reinterpret_cast<const float4*>(hs)[lane];
#pragma unroll
    for (int k = 0; k < 4; ++k) {
        const int c = 16 * g + wave * 4 + k;
        float4 w = reinterpret_cast<const float4*>(w2 + c * C)[lane];
        float o = (w.x * hv.x + w.y * hv.y) + (w.z * hv.z + w.w * hv.w);
#pragma unroll
        for (int off = 32; off > 0; off >>= 1) o += __shfl_down(o, off);
        if (lane == 0) ca_g[b * C + c] = 1.f / (1.f + expf(-o));
    }
}

// ---------------------------------------------------------------------------
// K3: WTA prologue + scale. 2048 blocks = (b, chunk); block owns 16 rows.
// Prologue: ca -> LDS, rank-count its 16 channels, sc = rank<KC ? ta*ca : 0.
// WTA: keep iff #{j: ca_j > ca_i} < 205; mask^2 == mask. Zero rows skip the
// x read. Plain dwordx4 stores. Measured ~41 us incl gap = copy floor.
// ---------------------------------------------------------------------------
__global__ __launch_bounds__(256) void k_scale(const float* __restrict__ x,
                                               const float* __restrict__ ta_g,
                                               const float* __restrict__ ca_g,
                                               float* __restrict__ out) {
    __shared__ float ca[C];
    __shared__ float pcnt[16][16];
    __shared__ float srow_s[16];
    const int b = blockIdx.x >> 7, chunk = blockIdx.x & 127;
    const int t = threadIdx.x;
    const int f = chunk >> 4, c0 = (chunk & 15) * 16;

    ca[t] = ca_g[b * C + t];
    __syncthreads();

    {
        const int ch = t >> 4, seg = t & 15;
        const float cav = ca[c0 + ch];
        int cnt = 0;
#pragma unroll
        for (int jj = 0; jj < 16; ++jj) cnt += (ca[seg * 16 + jj] > cav);
        pcnt[ch][seg] = (float)cnt;
    }
    __syncthreads();
    if (t < 16) {
        float r = 0.f;
#pragma unroll
        for (int s = 0; s < 16; ++s) r += pcnt[t][s];
        srow_s[t] = (((int)r) < KC) ? ta_g[b * F + f] * ca[c0 + t] : 0.f;
    }
    __syncthreads();

    const int row0 = blockIdx.x * 16;
    const f4* x4 = reinterpret_cast<const f4*>(x);
    f4* o4 = reinterpret_cast<f4*>(out);
#pragma unroll
    for (int g = 0; g < 4; ++g) {
        const size_t base = (size_t)(row0 + g * 4) * 256 + t;
        const float s0 = srow_s[g*4], s1 = srow_s[g*4+1];
        const float s2 = srow_s[g*4+2], s3 = srow_s[g*4+3];
        const f4 z = {0.f, 0.f, 0.f, 0.f};
        f4 v0 = z, v1 = z, v2 = z, v3 = z;
        if (s0 != 0.f) v0 = x4[base];
        if (s1 != 0.f) v1 = x4[base + 256];
        if (s2 != 0.f) v2 = x4[base + 512];
        if (s3 != 0.f) v3 = x4[base + 768];
        v0 *= s0; v1 *= s1; v2 *= s2; v3 *= s3;
        o4[base]       = v0;
        o4[base + 256] = v1;
        o4[base + 512] = v2;
        o4[base + 768] = v3;
    }
}

extern "C" void kernel_launch(void* const* d_in, const int* in_sizes, int n_in,
                              void* d_out, int out_size, void* d_ws, size_t ws_size,
                              hipStream_t stream) {
    const float* x     = (const float*)d_in[0];
    const float* ta_w1 = (const float*)d_in[1];
    const float* ta_w2 = (const float*)d_in[2];
    const float* ca_w1 = (const float*)d_in[3];
    const float* ca_w2 = (const float*)d_in[4];
    float* out = (float*)d_out;

    float* ws     = (float*)d_ws;
    float* sums   = ws;                      // [32768]
    float* maxs   = ws + NROWS;              // [32768]
    float* ta_g   = ws + 2 * NROWS;          // [128]
    float* hsum_g = ws + 2 * NROWS + 128;    // [4096]
    float* ca_g   = ws + 2 * NROWS + 128 + B * C;  // [4096]

    k_rowstat<<<NROWS / 8, 256, 0, stream>>>(x, sums, maxs);
    k_l1<<<B * 16, 256, 0, stream>>>(sums, maxs, ta_w1, ta_w2, ca_w1, ta_g, hsum_g);
    k_l2<<<B * 16, 256, 0, stream>>>(hsum_g, ca_w2, ca_g);
    k_scale<<<2048, 256, 0, stream>>>(x, ta_g, ca_g, out);
}